// Round 5
// baseline (54.951 us; speedup 1.0000x reference)
//
#include <hip/hip_runtime.h>

// Loss = (1/B) * sum_{b,i} min_j ||s[b,i]-t[b,j]||^2  (Cl(3) scalar part of v*v = ||v||^2).
// Track per point the min of h = 0.5||s||^2 + 0.5||t||^2 - s.t = 0.5*d2;
// loss = (1/4) * 2 * sum(h) = 0.5 * sum(h).
#define BATCH 4
#define NPTS 8192
#define NTOT (BATCH * NPTS)   // 32768

constexpr int THREADS   = 256;
constexpr int S_PER_THR = 8;                      // source points per thread (regs)
constexpr int SRC_CHUNK = THREADS * S_PER_THR;    // 2048
constexpr int NSC       = NPTS / SRC_CHUNK;       // 4
constexpr int TGT_CHUNK = 128;                    // targets per block (uniform reads)
constexpr int NTC       = NPTS / TGT_CHUNK;       // 64 slabs
constexpr int RBLOCKS   = 128;                    // NTOT = RBLOCKS * 256

// Pack targets as aligned float4 (x, y, z, 0.5*||t||^2) so the knn loop can read
// them with wave-uniform addresses (-> s_load_dwordx4 on the SMEM pipe, no LDS).
__global__ __launch_bounds__(256) void prep_kernel(
        const float* __restrict__ tgt, float4* __restrict__ tq) {
    int i = blockIdx.x * 256 + threadIdx.x;
    if (i < NTOT) {
        float x = tgt[3 * i + 0];
        float y = tgt[3 * i + 1];
        float z = tgt[3 * i + 2];
        tq[i] = make_float4(x, y, z, 0.5f * (x * x + y * y + z * z));
    }
}

// Block = (b, src-chunk, tgt-chunk). grid = 4*4*64 = 1024 blocks (4/CU).
// No LDS, no barriers: target reads are uniform; VALU is the only loaded pipe.
__global__ __launch_bounds__(THREADS) void knn_partial_kernel(
        const float* __restrict__ src,     // (B, P, 3)
        const float4* __restrict__ tq,     // (B*P) packed targets
        float* __restrict__ ws)            // (NTC, NTOT) partial h-mins
{
    int bid = blockIdx.x;
    int tc  = bid % NTC;
    int sc  = (bid / NTC) % NSC;
    int b   = bid / (NTC * NSC);

    // My 8 source points in registers.
    const float* sbase = src + ((size_t)b * NPTS + (size_t)sc * SRC_CHUNK) * 3;
    float sx[S_PER_THR], sy[S_PER_THR], sz[S_PER_THR], mb[S_PER_THR];
    #pragma unroll
    for (int s = 0; s < S_PER_THR; ++s) {
        int i = threadIdx.x + s * THREADS;
        sx[s] = sbase[3 * i + 0];
        sy[s] = sbase[3 * i + 1];
        sz[s] = sbase[3 * i + 2];
        mb[s] = INFINITY;
    }

    const float4* tbase = tq + (size_t)b * NPTS + (size_t)tc * TGT_CHUNK;

    // Per j-pair: 2 uniform 16B loads (SMEM pipe) + 8*(6 fma + 1 min3) VALU.
    #pragma unroll 4
    for (int j = 0; j < TGT_CHUNK; j += 2) {
        float4 t0 = tbase[j];
        float4 t1 = tbase[j + 1];
        #pragma unroll
        for (int s = 0; s < S_PER_THR; ++s) {
            float m0 = fmaf(-sx[s], t0.x, fmaf(-sy[s], t0.y, fmaf(-sz[s], t0.z, t0.w)));
            float m1 = fmaf(-sx[s], t1.x, fmaf(-sy[s], t1.y, fmaf(-sz[s], t1.z, t1.w)));
            mb[s] = fminf(mb[s], fminf(m0, m1));   // -> v_min3_f32
        }
    }

    // h = min_m + 0.5||s||^2 ; plain store into this target-chunk's slab.
    float* wbase = ws + (size_t)tc * NTOT + (size_t)b * NPTS + (size_t)sc * SRC_CHUNK;
    #pragma unroll
    for (int s = 0; s < S_PER_THR; ++s) {
        float hs = 0.5f * (sx[s] * sx[s] + sy[s] * sy[s] + sz[s] * sz[s]);
        wbase[threadIdx.x + s * THREADS] = mb[s] + hs;
    }
}

// Stage 1: 128 blocks, one point per thread: min across the 64 slabs, block tree-sum.
__global__ __launch_bounds__(256) void reduce1_kernel(
        const float* __restrict__ ws,
        float* __restrict__ partials)
{
    __shared__ float acc[256];
    int i = blockIdx.x * 256 + threadIdx.x;
    float m = INFINITY;
    #pragma unroll 8
    for (int sl = 0; sl < NTC; ++sl)
        m = fminf(m, ws[(size_t)sl * NTOT + i]);
    acc[threadIdx.x] = m;
    __syncthreads();
    for (int off = 128; off > 0; off >>= 1) {
        if (threadIdx.x < off) acc[threadIdx.x] += acc[threadIdx.x + off];
        __syncthreads();
    }
    if (threadIdx.x == 0) partials[blockIdx.x] = acc[0];
}

// Stage 2: one wave sums the 128 partials; loss = 0.5 * total.
__global__ __launch_bounds__(64) void reduce2_kernel(
        const float* __restrict__ partials,
        float* __restrict__ out)
{
    float v = partials[threadIdx.x] + partials[threadIdx.x + 64];
    #pragma unroll
    for (int off = 32; off > 0; off >>= 1)
        v += __shfl_down(v, off, 64);
    if (threadIdx.x == 0) out[0] = v * 0.5f;
}

extern "C" void kernel_launch(void* const* d_in, const int* in_sizes, int n_in,
                              void* d_out, int out_size, void* d_ws, size_t ws_size,
                              hipStream_t stream) {
    const float* src = (const float*)d_in[0];   // source_cloud (4, 8192, 3) f32
    const float* tgt = (const float*)d_in[1];   // target_cloud (4, 8192, 3) f32
    // d_in[2] = cayley (8,8,8) — Euclidean; scalar part of v*v == ||v||^2
    float* out = (float*)d_out;

    // Workspace layout: tq (512 KiB) | slabs (8 MiB) | partials (512 B)
    float4* tq       = (float4*)d_ws;
    float*  ws       = (float*)((char*)d_ws + (size_t)NTOT * sizeof(float4));
    float*  partials = (float*)((char*)ws + (size_t)NTC * NTOT * sizeof(float));

    prep_kernel<<<NTOT / 256, 256, 0, stream>>>(tgt, tq);
    knn_partial_kernel<<<BATCH * NSC * NTC, THREADS, 0, stream>>>(src, tq, ws);
    reduce1_kernel<<<RBLOCKS, 256, 0, stream>>>(ws, partials);
    reduce2_kernel<<<1, 64, 0, stream>>>(partials, out);
}

// Round 6
// 39.415 us; speedup vs baseline: 1.3942x; 1.3942x over previous
//
#include <hip/hip_runtime.h>

// Loss = (1/B) * sum_{b,i} min_j ||s[b,i]-t[b,j]||^2  (Cl(3) scalar part of v*v = ||v||^2).
// Track per point the min of h = 0.5||s||^2 + 0.5||t||^2 - s.t = 0.5*d2;
// loss = (1/4) * 2 * sum(h) = 0.5 * sum(h).
#define BATCH 4
#define NPTS 8192
#define NTOT (BATCH * NPTS)   // 32768

constexpr int THREADS   = 256;
constexpr int S_PER_THR = 8;                      // source points per thread (regs)
constexpr int SRC_CHUNK = THREADS * S_PER_THR;    // 2048
constexpr int NSC       = NPTS / SRC_CHUNK;       // 4
constexpr int TGT_CHUNK = 256;                    // targets staged in LDS (R3 config)
constexpr int NTC       = NPTS / TGT_CHUNK;       // 32 slabs
constexpr int RBLOCKS   = 128;                    // NTOT = RBLOCKS * 256

// ---- knn: byte-identical compute to R3 (33.2 µs best), plus counter reset. ----
__global__ __launch_bounds__(THREADS) void knn_partial_kernel(
        const float* __restrict__ src,   // (B, P, 3)
        const float* __restrict__ tgt,   // (B, P, 3)
        float* __restrict__ ws,          // (NTC, NTOT) partial h-mins
        unsigned* __restrict__ counter)  // reset here; used by fused reduce
{
    if (blockIdx.x == 0 && threadIdx.x == 0) counter[0] = 0u;  // knn precedes reduce

    int bid = blockIdx.x;
    int tc  = bid % NTC;
    int sc  = (bid / NTC) % NSC;
    int b   = bid / (NTC * NSC);

    __shared__ float4 tsh[TGT_CHUNK];

    // Stage target tile: (x, y, z, 0.5*||t||^2). One point per thread.
    {
        const float* tbase = tgt + ((size_t)b * NPTS + (size_t)tc * TGT_CHUNK) * 3;
        int k = threadIdx.x;
        float x = tbase[3 * k + 0];
        float y = tbase[3 * k + 1];
        float z = tbase[3 * k + 2];
        tsh[k] = make_float4(x, y, z, 0.5f * (x * x + y * y + z * z));
    }

    // My 8 source points in registers.
    const float* sbase = src + ((size_t)b * NPTS + (size_t)sc * SRC_CHUNK) * 3;
    float sx[S_PER_THR], sy[S_PER_THR], sz[S_PER_THR], mb[S_PER_THR];
    #pragma unroll
    for (int s = 0; s < S_PER_THR; ++s) {
        int i = threadIdx.x + s * THREADS;
        sx[s] = sbase[3 * i + 0];
        sy[s] = sbase[3 * i + 1];
        sz[s] = sbase[3 * i + 2];
        mb[s] = INFINITY;
    }
    __syncthreads();

    // Per j-pair per thread: 2 broadcast ds_read_b128 + 8*(6 fma + 1 min3).
    #pragma unroll 4
    for (int j = 0; j < TGT_CHUNK; j += 2) {
        float4 t0 = tsh[j];
        float4 t1 = tsh[j + 1];
        #pragma unroll
        for (int s = 0; s < S_PER_THR; ++s) {
            float m0 = fmaf(-sx[s], t0.x, fmaf(-sy[s], t0.y, fmaf(-sz[s], t0.z, t0.w)));
            float m1 = fmaf(-sx[s], t1.x, fmaf(-sy[s], t1.y, fmaf(-sz[s], t1.z, t1.w)));
            mb[s] = fminf(mb[s], fminf(m0, m1));   // -> v_min3_f32
        }
    }

    // h = min_m + 0.5||s||^2 ; plain store into this target-chunk's slab.
    float* wbase = ws + (size_t)tc * NTOT + (size_t)b * NPTS + (size_t)sc * SRC_CHUNK;
    #pragma unroll
    for (int s = 0; s < S_PER_THR; ++s) {
        float hs = 0.5f * (sx[s] * sx[s] + sy[s] * sy[s] + sz[s] * sz[s]);
        wbase[threadIdx.x + s * THREADS] = mb[s] + hs;
    }
}

// ---- Fused reduce: slab-min + block tree-sum + last-done block finishes. ----
// Deterministic: per-block partials are fixed; the final sum is a fixed tree
// order over partials[0..127] regardless of which block runs it.
__global__ __launch_bounds__(256) void reduce_fused_kernel(
        const float* __restrict__ ws,
        float* __restrict__ partials,     // 128 floats
        unsigned* __restrict__ counter,   // reset by knn each call
        float* __restrict__ out)
{
    __shared__ float acc[256];
    __shared__ unsigned my_rank;

    int i = blockIdx.x * 256 + threadIdx.x;     // one point per thread
    float m = INFINITY;
    #pragma unroll 8
    for (int sl = 0; sl < NTC; ++sl)
        m = fminf(m, ws[(size_t)sl * NTOT + i]);

    acc[threadIdx.x] = m;
    __syncthreads();
    for (int off = 128; off > 0; off >>= 1) {
        if (threadIdx.x < off) acc[threadIdx.x] += acc[threadIdx.x + off];
        __syncthreads();
    }
    if (threadIdx.x == 0) {
        atomicExch(&partials[blockIdx.x], acc[0]);  // device-scope publish
        __threadfence();
        my_rank = atomicAdd(counter, 1u);
    }
    __syncthreads();

    if (my_rank == RBLOCKS - 1) {               // last block finishes
        __threadfence();
        float v = (threadIdx.x < RBLOCKS) ? atomicAdd(&partials[threadIdx.x], 0.0f)
                                          : 0.0f;
        acc[threadIdx.x] = v;
        __syncthreads();
        for (int off = 128; off > 0; off >>= 1) {
            if (threadIdx.x < off) acc[threadIdx.x] += acc[threadIdx.x + off];
            __syncthreads();
        }
        if (threadIdx.x == 0) out[0] = acc[0] * 0.5f;
    }
}

extern "C" void kernel_launch(void* const* d_in, const int* in_sizes, int n_in,
                              void* d_out, int out_size, void* d_ws, size_t ws_size,
                              hipStream_t stream) {
    const float* src = (const float*)d_in[0];   // source_cloud (4, 8192, 3) f32
    const float* tgt = (const float*)d_in[1];   // target_cloud (4, 8192, 3) f32
    // d_in[2] = cayley (8,8,8) — Euclidean; scalar part of v*v == ||v||^2
    float* out = (float*)d_out;

    // Workspace: slabs (4 MiB) | partials (512 B) | counter (4 B)
    float*    ws       = (float*)d_ws;
    float*    partials = (float*)((char*)d_ws + (size_t)NTC * NTOT * sizeof(float));
    unsigned* counter  = (unsigned*)((char*)partials + RBLOCKS * sizeof(float));

    knn_partial_kernel<<<BATCH * NSC * NTC, THREADS, 0, stream>>>(src, tgt, ws, counter);
    reduce_fused_kernel<<<RBLOCKS, 256, 0, stream>>>(ws, partials, counter, out);
}